// Round 12
// baseline (475.145 us; speedup 1.0000x reference)
//
#include <hip/hip_runtime.h>
#include <cstdint>
#include <cstddef>
#include <utility>

#define Ndim 8
#define Odim 32
#define Cdim 16
#define Hdim 512
#define Rdim 8
#define TW 64
#define TH 4
#define NBW (Hdim/TW)     // 8   w-blocks
#define NBH (Hdim/TH)     // 128 h-blocks
#define HHsz ((size_t)Hdim*Hdim)

typedef _Float16 half2_t __attribute__((ext_vector_type(2)));
typedef __fp16 fp16x2_t __attribute__((ext_vector_type(2)));
typedef unsigned int u32x4 __attribute__((ext_vector_type(4)));

union U16 { u32x4 u; half2_t h[4]; };
union UPK { fp16x2_t f; half2_t h; unsigned int u; };

template <class F, int... Is>
__device__ __forceinline__ void unroll_impl(F&& f, std::integer_sequence<int, Is...>) {
    (f(std::integral_constant<int, Is>{}), ...);
}
template <int N, class F>
__device__ __forceinline__ void unrollN(F&& f) {
    unroll_impl(static_cast<F&&>(f), std::make_integer_sequence<int, N>{});
}

// RTN pack (cold paths: X, L)
__device__ __forceinline__ half2_t pk(float a, float b) {
    half2_t h; h[0] = (_Float16)a; h[1] = (_Float16)b; return h;
}

#if defined(__has_builtin)
#if __has_builtin(__builtin_amdgcn_cvt_pkrtz)
#define HAVE_PKRTZ 1
#endif
#if __has_builtin(__builtin_amdgcn_fdot2)
#define HAVE_FDOT2 1
#endif
#endif

// RTZ pack (hot path: P store) — single v_cvt_pkrtz_f16_f32; bit-cast fixes the
// __fp16-vs-_Float16 vector type mismatch that broke round 11's compile.
__device__ __forceinline__ half2_t pkz(float a, float b) {
#ifdef HAVE_PKRTZ
    UPK u; u.f = __builtin_amdgcn_cvt_pkrtz(a, b);
    return u.h;
#else
    return pk(a, b);
#endif
}

__device__ __forceinline__ float fdot2f(half2_t a, half2_t b, float acc) {
#ifdef HAVE_FDOT2
    return __builtin_amdgcn_fdot2(a, b, acc, false);
#else
    return acc + (float)a[0] * (float)b[0] + (float)a[1] * (float)b[1];
#endif
}

__device__ __forceinline__ void stage16(const u32x4* g, u32x4* l) {
    __builtin_amdgcn_global_load_lds(
        (const __attribute__((address_space(1))) uint32_t*)g,
        (__attribute__((address_space(3))) uint32_t*)l, 16, 0, 0);
}

template<int CTRL>
__device__ __forceinline__ float dppadd(float v) {
    return v + __int_as_float(__builtin_amdgcn_update_dpp(
        0, __float_as_int(v), CTRL, 0xf, 0xf, true));
}
__device__ __forceinline__ float wave_sum63(float v) {
    v = dppadd<0xB1>(v);
    v = dppadd<0x4E>(v);
    v = dppadd<0x141>(v);
    v = dppadd<0x140>(v);
    v = dppadd<0x142>(v);
    v = dppadd<0x143>(v);
    return v;
}

// ---- L prep: lsigT[(o*H+h)*C+c] = f16(L*coup); lraw[(o*C+c)*H+w] = f16(L) ----
__global__ __launch_bounds__(256)
void sylo_prep(const float* __restrict__ L, const float* __restrict__ coup,
               u32x4* __restrict__ lsigT, u32x4* __restrict__ lraw)
{
    int row = blockIdx.x * 256 + threadIdx.x;      // (o*C + c)*H + h
    int oc = row >> 9, h = row & 511;
    int o = oc >> 4, c = oc & 15;
    const float4* lp = (const float4*)(L + (size_t)row * Rdim);
    const float4* cp = (const float4*)(coup + (size_t)oc * Rdim);
    float4 l0 = lp[0], l1 = lp[1];
    float4 c0 = cp[0], c1 = cp[1];
    U16 s, r;
    s.h[0] = pk(l0.x * c0.x, l0.y * c0.y); s.h[1] = pk(l0.z * c0.z, l0.w * c0.w);
    s.h[2] = pk(l1.x * c1.x, l1.y * c1.y); s.h[3] = pk(l1.z * c1.z, l1.w * c1.w);
    r.h[0] = pk(l0.x, l0.y); r.h[1] = pk(l0.z, l0.w);
    r.h[2] = pk(l1.x, l1.y); r.h[3] = pk(l1.z, l1.w);
    lsigT[((size_t)o * Hdim + h) * Cdim + c] = s.u;
    lraw[row] = r.u;
}

// ---- staging helpers ----
__device__ __forceinline__ void stage_tile(const u32x4* __restrict__ lraw, int o,
                                           int w0, int j, int iw, u32x4 (&buf)[Cdim][TW])
{
    unrollN<4>([&](auto ki) {
        constexpr int k = decltype(ki)::value;
        int c = iw * 4 + k;
        stage16(lraw + ((size_t)(o * Cdim + c) * Hdim + w0 + j), &buf[c][0]);
    });
}
__device__ __forceinline__ void stage_tile_raw(const float* __restrict__ Lg, int o,
                                               int w0, int tid, u32x4 (&buf)[Cdim][TW])
{
    unrollN<4>([&](auto ki) {
        constexpr int k = decltype(ki)::value;
        int e = tid + k * 256, c = e >> 6, w = e & 63;
        const float4* gp = (const float4*)(Lg + ((size_t)(o * Cdim + c) * Hdim + w0 + w) * Rdim);
        float4 l0 = gp[0], l1 = gp[1];
        U16 t;
        t.h[0] = pk(l0.x, l0.y); t.h[1] = pk(l0.z, l0.w);
        t.h[2] = pk(l1.x, l1.y); t.h[3] = pk(l1.z, l1.w);
        buf[c][w] = t.u;
    });
}

// ---- fused T+P; X from per-o re-read of packed slice (opaque offset defeats LICM) ----
template<int XH, int LP>
__device__ __forceinline__ void compute_core(
    int o, int ruh, int j, int tid,
    const u32x4 (&lwb)[Cdim][TW], const u32x4* xsl,
    const float* __restrict__ Xg, size_t q,
    const u32x4* __restrict__ lsigT, const float* __restrict__ Lg,
    const float* __restrict__ coupg, float (&p)[Ndim])
{
    unrollN<8>([&](auto ni) { p[decltype(ni)::value] = 0.f; });
    unsigned xofs = 0;
    if constexpr (XH) { asm volatile("" : "+v"(xofs)); }   // fresh per call -> no hoist
    unrollN<8>([&](auto cpi) {
        constexpr int cp = decltype(cpi)::value;
        U16 x0, x1;
        if constexpr (XH) {
            x0.u = xsl[xofs + (2 * cp) * 256 + tid];
            x1.u = xsl[xofs + (2 * cp + 1) * 256 + tid];
        } else {
            unrollN<4>([&](auto ni) { constexpr int n = decltype(ni)::value;
                x0.h[n] = pk(Xg[(size_t)(n * Cdim + 2 * cp) * HHsz + q],
                             Xg[(size_t)(n * Cdim + 2 * cp + 1) * HHsz + q]); });
            unrollN<4>([&](auto ni) { constexpr int n = decltype(ni)::value;
                x1.h[n] = pk(Xg[(size_t)((n + 4) * Cdim + 2 * cp) * HHsz + q],
                             Xg[(size_t)((n + 4) * Cdim + 2 * cp + 1) * HHsz + q]); });
        }
        float tv0 = 0.f, tv1 = 0.f;
        unrollN<2>([&](auto hi) {
            constexpr int hf = decltype(hi)::value;
            constexpr int c = 2 * cp + hf;
            U16 A, B;
            if constexpr (LP) {
                A.u = lsigT[((size_t)o * Hdim + ruh) * Cdim + c];
            } else {
                const float4* a0 = (const float4*)(Lg + ((size_t)(o * Cdim + c) * Hdim + ruh) * Rdim);
                const float4* cpp = (const float4*)(coupg + (size_t)(o * Cdim + c) * Rdim);
                float4 l0 = a0[0], l1 = a0[1];
                float4 c0 = cpp[0], c1 = cpp[1];
                A.h[0] = pk(l0.x * c0.x, l0.y * c0.y); A.h[1] = pk(l0.z * c0.z, l0.w * c0.w);
                A.h[2] = pk(l1.x * c1.x, l1.y * c1.y); A.h[3] = pk(l1.z * c1.z, l1.w * c1.w);
            }
            B.u = lwb[c][j];
            float t = 0.f;
            unrollN<4>([&](auto ri) {
                constexpr int r = decltype(ri)::value;
                t = fdot2f(A.h[r], B.h[r], t);
            });
            if constexpr (hf == 0) tv0 = t; else tv1 = t;
        });
        half2_t t2 = pk(tv0, tv1);
        unrollN<4>([&](auto ni) { constexpr int n = decltype(ni)::value;
            p[n] = fdot2f(t2, x0.h[n], p[n]); });
        unrollN<4>([&](auto ni) { constexpr int n = decltype(ni)::value;
            p[n + 4] = fdot2f(t2, x1.h[n], p[n + 4]); });
        if constexpr (cp == 1 || cp == 3 || cp == 5)
            __builtin_amdgcn_sched_barrier(0);
    });
}

// ---- P-producer: P -> pf (f16 packed), rs (DPP+atomic), cs (LDS flush + atomic) ----
template<int BXH, int XH, int LP, int PF>
__global__ __launch_bounds__(256, 4)
void sylo_p0(const float* __restrict__ Xg, const float* __restrict__ Lg,
             const float* __restrict__ coupg,
             const u32x4* __restrict__ lsigT, const u32x4* __restrict__ lraw,
             u32x4* __restrict__ xh, u32x4* __restrict__ pf,
             float* __restrict__ rs, float* __restrict__ cs,
             int obase, int ocount)
{
    const int tid = threadIdx.x;
    const int j = tid & 63, iw = tid >> 6;
    const int bw = blockIdx.x, bh = blockIdx.y;
    const int w0 = bw * TW;
    const int hh = bh * TH + iw, ww = w0 + j;
    const size_t q = (size_t)hh * Hdim + ww;

    __shared__ __align__(16) u32x4 lw[2][Cdim][TW];   // 32 KB dbuf
    __shared__ float csl[TH][Ndim][TW];               // 8 KB

    u32x4* xsl = nullptr;
    if constexpr (XH) xsl = xh + (size_t)(bh * NBW + bw) * 4096;

    if constexpr (BXH) {   // build block-private packed X slice once (chunk 0)
        unrollN<16>([&](auto ki) {
            constexpr int k = decltype(ki)::value;
            U16 v;
            unrollN<4>([&](auto ii) {
                constexpr int i = decltype(ii)::value;
                constexpr int pr = 4 * k + i;      // pair = cp*8 + n
                constexpr int cp = pr >> 3, n = pr & 7;
                v.h[i] = pk(Xg[(size_t)(n * Cdim + 2 * cp) * HHsz + q],
                            Xg[(size_t)(n * Cdim + 2 * cp + 1) * HHsz + q]);
            });
            xsl[k * 256 + tid] = v.u;              // coalesced per k
            if constexpr (k == 3 || k == 7 || k == 11) __builtin_amdgcn_sched_barrier(0);
        });
    }

    const int ruh = __builtin_amdgcn_readfirstlane(hh);

    if (LP) stage_tile(lraw, obase, w0, j, iw, lw[0]);
    __syncthreads();   // drains xsl stores + prologue stage

    for (int oo = 0; oo < ocount; ++oo) {
        const int o = obase + oo;
        const int cur = LP ? (oo & 1) : 0;
        if (LP) {
            if (oo + 1 < ocount) stage_tile(lraw, o + 1, w0, j, iw, lw[cur ^ 1]);
        } else {
            stage_tile_raw(Lg, o, w0, tid, lw[0]);
            __syncthreads();
        }

        float p[Ndim];
        compute_core<XH, LP>(o, ruh, j, tid, lw[cur], xsl, Xg, q, lsigT, Lg, coupg, p);

        if constexpr (PF) {   // packed f16 P: [oo][h][w] x uint4(8 n's)
            U16 pv;
            unrollN<4>([&](auto ki) {
                constexpr int k = decltype(ki)::value;
                pv.h[k] = pkz(p[2 * k], p[2 * k + 1]);
            });
            pf[((size_t)oo * Hdim + hh) * Hdim + ww] = pv.u;
        }

        unrollN<8>([&](auto ni) {
            constexpr int n = decltype(ni)::value;
            float r = wave_sum63(p[n]);
            if (j == 63) atomicAdd(&rs[(size_t)(n * Odim + o) * Hdim + hh], r);
            csl[iw][n][j] = p[n];
        });
        __syncthreads();
        unrollN<2>([&](auto ki) {
            constexpr int k = decltype(ki)::value;
            int f = tid + k * 256;
            int n = f >> 6, jj = f & 63;
            float v = csl[0][n][jj] + csl[1][n][jj] + csl[2][n][jj] + csl[3][n][jj];
            atomicAdd(&cs[(size_t)(n * Odim + o) * Hdim + w0 + jj], v);
        });
        __syncthreads();   // csl + dbuf reusable; drains this iter's stage DMA
    }
}

// ---- pure-streaming finalize: out = rs + cs - P + bias, diag zeroed ----
__global__ __launch_bounds__(256)
void sylo_p1s(const u32x4* __restrict__ pf, const float* __restrict__ rs,
              const float* __restrict__ cs, const float* __restrict__ biasg,
              float* __restrict__ outg, int obase, int OL)
{
    const int tid = threadIdx.x;
    const int j = tid & 63, iw = tid >> 6;
    const int bw = blockIdx.x, bh = blockIdx.y;
    const int hh = bh * TH + iw, ww = bw * TW + j;
    const int ruh = __builtin_amdgcn_readfirstlane(hh);

    for (int oo = 0; oo < OL; ++oo) {
        const int oc = blockIdx.z * OL + oo;     // chunk-local o
        const int o = obase + oc;
        U16 pv;
        pv.u = pf[((size_t)oc * Hdim + hh) * Hdim + ww];
        float bb = biasg[o];
        unrollN<4>([&](auto ki) {
            constexpr int k = decltype(ki)::value;
            constexpr int n0 = 2 * k, n1 = 2 * k + 1;
            float pa = (float)pv.h[k][0], pb = (float)pv.h[k][1];
            size_t i0 = (size_t)(n0 * Odim + o) * Hdim;
            size_t i1 = (size_t)(n1 * Odim + o) * Hdim;
            float v0 = rs[i0 + (size_t)ruh] + cs[i0 + ww] - pa + bb;
            float v1 = rs[i1 + (size_t)ruh] + cs[i1 + ww] - pb + bb;
            if (hh == ww) { v0 = 0.f; v1 = 0.f; }
            outg[(i0 + hh) * Hdim + ww] = v0;
            outg[(i1 + hh) * Hdim + ww] = v1;
        });
    }
}

// ---- recompute finalize (only for the no-ws insurance tier) ----
__global__ __launch_bounds__(256, 4)
void sylo_p1r(const float* __restrict__ Xg, const float* __restrict__ Lg,
              const float* __restrict__ coupg, const float* __restrict__ biasg,
              float* __restrict__ outg,
              const float* __restrict__ rs, const float* __restrict__ cs)
{
    const int tid = threadIdx.x;
    const int j = tid & 63, iw = tid >> 6;
    const int bw = blockIdx.x, bh = blockIdx.y;
    const int w0 = bw * TW;
    const int hh = bh * TH + iw, ww = w0 + j;
    const size_t q = (size_t)hh * Hdim + ww;
    __shared__ __align__(16) u32x4 lw[2][Cdim][TW];
    const int ruh = __builtin_amdgcn_readfirstlane(hh);

    for (int o = 0; o < Odim; ++o) {
        __syncthreads();
        stage_tile_raw(Lg, o, w0, tid, lw[0]);
        __syncthreads();
        float p[Ndim];
        compute_core<0, 0>(o, ruh, j, tid, lw[0], nullptr, Xg, q, nullptr, Lg, coupg, p);
        float bb = biasg[o];
        unrollN<8>([&](auto ni) {
            constexpr int n = decltype(ni)::value;
            size_t i0 = (size_t)(n * Odim + o) * Hdim;
            float v = rs[i0 + (size_t)ruh] + cs[i0 + ww] - p[n] + bb;
            if (hh == ww) v = 0.f;
            outg[(i0 + hh) * Hdim + ww] = v;
        });
    }
}

extern "C" void kernel_launch(void* const* d_in, const int* in_sizes, int n_in,
                              void* d_out, int out_size, void* d_ws, size_t ws_size,
                              hipStream_t stream)
{
    const float* X    = (const float*)d_in[0];
    const float* L    = (const float*)d_in[1];
    const float* bias = (const float*)d_in[2];
    const float* coup = (const float*)d_in[3];
    float* out = (float*)d_out;

    const size_t S     = (size_t)Ndim * Odim * Hdim;   // 131072
    const size_t NL16  = (size_t)Odim * Cdim * Hdim;   // 262144 uint4
    const size_t NXH   = (size_t)1024 * 4096;          // 4194304 uint4 (67MB)
    const size_t pfPerO = HHsz * 16;                   // 4 MiB per o

    int C = 0, XH = 0, LP = 0;
    auto tier = [&](int xh_, int lp_) {
        size_t base = (lp_ ? 2 * NL16 * 16 : 0) + (xh_ ? NXH * 16 : 0) + 2 * S * 4;
        const int cands[6] = {32, 16, 8, 4, 2, 1};
        for (int i = 0; i < 6; ++i)
            if (ws_size >= base + (size_t)cands[i] * pfPerO) { C = cands[i]; XH = xh_; LP = lp_; return true; }
        return false;
    };
    dim3 g(NBW, NBH), b(256);

    if (tier(1, 1) || tier(0, 1) || tier(0, 0)) {
        char* p = (char*)d_ws;
        u32x4 *lsigT = nullptr, *lraw = nullptr, *xh = nullptr, *pf;
        if (LP) { lsigT = (u32x4*)p; p += NL16 * 16; lraw = (u32x4*)p; p += NL16 * 16; }
        if (XH) { xh = (u32x4*)p; p += NXH * 16; }
        pf = (u32x4*)p; p += (size_t)C * pfPerO;
        float* rs = (float*)p;
        float* cs = rs + S;
        (void)hipMemsetAsync(rs, 0, 2 * S * sizeof(float), stream);
        if (LP) sylo_prep<<<dim3(1024), b, 0, stream>>>(L, coup, lsigT, lraw);

        for (int ob = 0; ob < Odim; ob += C) {
            if (XH) {
                if (ob == 0) sylo_p0<1,1,1,1><<<g, b, 0, stream>>>(X, L, coup, lsigT, lraw, xh, pf, rs, cs, ob, C);
                else         sylo_p0<0,1,1,1><<<g, b, 0, stream>>>(X, L, coup, lsigT, lraw, xh, pf, rs, cs, ob, C);
            } else if (LP) {
                sylo_p0<0,0,1,1><<<g, b, 0, stream>>>(X, L, coup, lsigT, lraw, nullptr, pf, rs, cs, ob, C);
            } else {
                sylo_p0<0,0,0,1><<<g, b, 0, stream>>>(X, L, coup, nullptr, nullptr, nullptr, pf, rs, cs, ob, C);
            }
            int OL = (C > 16) ? 16 : C;
            dim3 g2(NBW, NBH, C / OL);
            sylo_p1s<<<g2, b, 0, stream>>>(pf, rs, cs, bias, out, ob, OL);
        }
    } else {
        // insurance: minimal ws (~1MB): atomics + full recompute
        float* rs = (float*)d_ws;
        float* cs = rs + S;
        (void)hipMemsetAsync(rs, 0, 2 * S * sizeof(float), stream);
        sylo_p0<0,0,0,0><<<g, b, 0, stream>>>(X, L, coup, nullptr, nullptr, nullptr, nullptr, rs, cs, 0, Odim);
        sylo_p1r<<<g, b, 0, stream>>>(X, L, coup, bias, out, rs, cs);
    }
}